// Round 6
// baseline (2497.893 us; speedup 1.0000x reference)
//
#include <hip/hip_runtime.h>
#include <math.h>

#define D_IN 100
#define H    100
#define SEQL 30

typedef __attribute__((ext_vector_type(8))) short bf16x8;
typedef __attribute__((ext_vector_type(4))) float f32x4;

__device__ __forceinline__ short f2bf(float f) {
    unsigned u = __builtin_bit_cast(unsigned, f);
    unsigned r = (u + 0x7FFFu + ((u >> 16) & 1u)) >> 16;
    return (short)r;
}
__device__ __forceinline__ float bf2f(short s) {
    unsigned u = ((unsigned)(unsigned short)s) << 16;
    return __builtin_bit_cast(float, u);
}

// ---------------------------------------------------------------------------
// Wemb = emb @ W_ih^T + b_ih. W_ih transposed into LDS; each thread produces
// float4 quads for TWO emb rows (v, v+32) sharing the same W reads -> LDS
// read traffic halved vs round 5 (its dominant cost).
// ---------------------------------------------------------------------------
__global__ __launch_bounds__(512) void k_wemb_t(const float* __restrict__ emb,
                                                const float* __restrict__ W_ih,
                                                const float* __restrict__ b_ih,
                                                float* __restrict__ Wemb, int V) {
    __shared__ float sWT[100 * 300];   // [d][g], 120KB
    __shared__ float sb[300];
    for (int i = threadIdx.x; i < 30000; i += 512) {
        int g = i / 100, d = i % 100;
        sWT[d * 300 + g] = W_ih[i];
    }
    for (int i = threadIdx.x; i < 300; i += 512) sb[i] = b_ih[i];
    __syncthreads();

    int v0 = blockIdx.x * 64;
    for (int t = threadIdx.x; t < 32 * 75; t += 512) {
        int vl = t / 75, gq = t % 75;
        int va = v0 + vl, vb = va + 32;
        int vca = va < V ? va : V - 1;
        int vcb = vb < V ? vb : V - 1;
        const float4* ea = (const float4*)(emb + (long)vca * 100);
        const float4* eb = (const float4*)(emb + (long)vcb * 100);
        float4 bq = *(const float4*)&sb[4 * gq];
        float4 accA = bq, accB = bq;
#pragma unroll
        for (int d4 = 0; d4 < 25; ++d4) {
            float4 w0 = *(const float4*)&sWT[(4 * d4 + 0) * 300 + 4 * gq];
            float4 w1 = *(const float4*)&sWT[(4 * d4 + 1) * 300 + 4 * gq];
            float4 w2 = *(const float4*)&sWT[(4 * d4 + 2) * 300 + 4 * gq];
            float4 w3 = *(const float4*)&sWT[(4 * d4 + 3) * 300 + 4 * gq];
            float4 eva = ea[d4], evb = eb[d4];
            accA.x = fmaf(eva.x, w0.x, fmaf(eva.y, w1.x, fmaf(eva.z, w2.x, fmaf(eva.w, w3.x, accA.x))));
            accA.y = fmaf(eva.x, w0.y, fmaf(eva.y, w1.y, fmaf(eva.z, w2.y, fmaf(eva.w, w3.y, accA.y))));
            accA.z = fmaf(eva.x, w0.z, fmaf(eva.y, w1.z, fmaf(eva.z, w2.z, fmaf(eva.w, w3.z, accA.z))));
            accA.w = fmaf(eva.x, w0.w, fmaf(eva.y, w1.w, fmaf(eva.z, w2.w, fmaf(eva.w, w3.w, accA.w))));
            accB.x = fmaf(evb.x, w0.x, fmaf(evb.y, w1.x, fmaf(evb.z, w2.x, fmaf(evb.w, w3.x, accB.x))));
            accB.y = fmaf(evb.x, w0.y, fmaf(evb.y, w1.y, fmaf(evb.z, w2.y, fmaf(evb.w, w3.y, accB.y))));
            accB.z = fmaf(evb.x, w0.z, fmaf(evb.y, w1.z, fmaf(evb.z, w2.z, fmaf(evb.w, w3.z, accB.z))));
            accB.w = fmaf(evb.x, w0.w, fmaf(evb.y, w1.w, fmaf(evb.z, w2.w, fmaf(evb.w, w3.w, accB.w))));
        }
        if (va < V) *(float4*)(Wemb + (long)va * 300 + 4 * gq) = accA;
        if (vb < V) *(float4*)(Wemb + (long)vb * 300 + 4 * gq) = accB;
    }
}

// ---------------------------------------------------------------------------
// Pack W_hh^T into MFMA-B-fragment-major bf16 hi/lo tables (layout verified).
// ---------------------------------------------------------------------------
__global__ void k_bpack(const float* __restrict__ W_hh, short* __restrict__ Bhi,
                        short* __restrict__ Blo, int total /* 43008 */) {
    int t = blockIdx.x * blockDim.x + threadIdx.x;
    if (t >= total) return;
    int i    = t & 7;
    int lane = (t >> 3) & 63;
    int blk  = t >> 9;            // nt*4 + ks
    int ks = blk & 3, nt = blk >> 2;
    int np = nt * 16 + (lane & 15);
    int k  = ks * 32 + ((lane >> 4) << 3) + i;
    int g = np / 112, j = np % 112;
    float v = (j < 100 && k < 100) ? W_hh[(g * 100 + j) * 100 + k] : 0.f;
    short hi = f2bf(v);
    short lo = f2bf(v - bf2f(hi));
    Bhi[t] = hi;
    Blo[t] = lo;
}

// ---------------------------------------------------------------------------
// MFMA GRU, round 6: 7 waves/block, 64 nodes/block (4 node-groups of 16).
// Round-5 diagnosis: __syncthreads drains vmcnt(0) each step; at 1 block/CU
// the 12-gather L2-miss latency (~800 cyc) was paid every step with only
// ~1000 cyc of work to hide it (4570 cyc/step measured). Fix: 4x work per
// step (144 MFMAs/wave), 4x fewer block-rounds (14.65 -> 4); all 48 gathers
// issue at step top, consumed group-by-group -> drained for free by step end.
// B frags register-resident (structure verified rounds 4-5). h_old re-read
// from the stable current LDS buffer (saves 16 VGPRs vs register carry).
// ---------------------------------------------------------------------------
__global__ __launch_bounds__(448, 2) void k_gru_mfma(
        const int* __restrict__ tok, const float* __restrict__ h0,
        const float* __restrict__ Wemb, const short* __restrict__ Bhi,
        const short* __restrict__ Blo, const float* __restrict__ b_hh,
        float* __restrict__ hout, int n_nodes) {
    __shared__ short hA[2][2][64 * 136];   // [buf][hi/lo][node*136+k], 68 KB

    const int tid  = threadIdx.x;
    const int w    = tid >> 6;
    const int lane = tid & 63;
    const int n0   = lane & 15;
    const int q    = lane >> 4;
    const int node0 = blockIdx.x * 64;

    // ---- B fragments: 3 gates x 4 k-steps, hi+lo, loaded once ----
    bf16x8 bh[3][4], bl[3][4];
#pragma unroll
    for (int g = 0; g < 3; ++g)
#pragma unroll
        for (int ks = 0; ks < 4; ++ks) {
            long bo = ((long)((g * 7 + w) * 4 + ks) * 64 + lane) * 8;
            bh[g][ks] = *(const bf16x8*)&Bhi[bo];
            bl[g][ks] = *(const bf16x8*)&Blo[bo];
        }

    // ---- init h tables (both buffers zero-padded at k=100..127) ----
    for (int i = tid; i < 64 * 128; i += 448) {
        int nd = i >> 7, c = i & 127;
        int row = node0 + nd; if (row >= n_nodes) row = n_nodes - 1;
        float v = (c < 100) ? h0[(long)row * 100 + c] : 0.f;
        short hi = f2bf(v);
        hA[0][0][nd * 136 + c] = hi;
        hA[0][1][nd * 136 + c] = f2bf(v - bf2f(hi));
        hA[1][0][nd * 136 + c] = 0;
        hA[1][1][nd * 136 + c] = 0;
    }

    const int j   = 16 * w + n0;
    const int jc  = j < 100 ? j : 99;
    const bool jok = (j < 100);
    const float bhr = b_hh[jc], bhz = b_hh[100 + jc], bhn = b_hh[200 + jc];

    __syncthreads();

    // ---- tokens for step 0, pre-scaled by 300 (cell c = G*4 + r) ----
    int tcur[16];
#pragma unroll
    for (int c = 0; c < 16; ++c) {
        int row = node0 + 16 * (c >> 2) + 4 * q + (c & 3);
        if (row >= n_nodes) row = n_nodes - 1;
        tcur[c] = tok[(long)row * SEQL] * 300;
    }

    int cur = 0;
#pragma unroll 1
    for (int l = 0; l < SEQL; ++l) {
        // ---- issue ALL current-step wx gathers up front (imm-offset trio) ----
        float wx[16][3];
#pragma unroll
        for (int c = 0; c < 16; ++c) {
            const float* wp = Wemb + (long)tcur[c] + jc;
            wx[c][0] = wp[0];
            wx[c][1] = wp[100];
            wx[c][2] = wp[200];
        }
        // ---- prefetch next step's tokens ----
        if (l < SEQL - 1) {
#pragma unroll
            for (int c = 0; c < 16; ++c) {
                int row = node0 + 16 * (c >> 2) + 4 * q + (c & 3);
                if (row >= n_nodes) row = n_nodes - 1;
                tcur[c] = tok[(long)row * SEQL + l + 1] * 300;
            }
        }

        const short* hc0 = &hA[cur][0][0];
        const short* hc1 = &hA[cur][1][0];
        short* hn0 = &hA[cur ^ 1][0][0];
        short* hn1 = &hA[cur ^ 1][1][0];

#pragma unroll
        for (int G = 0; G < 4; ++G) {
            // A-fragments for this node-group
            bf16x8 aHi[4], aLo[4];
#pragma unroll
            for (int ks = 0; ks < 4; ++ks) {
                int off = (16 * G + n0) * 136 + ks * 32 + q * 8;
                aHi[ks] = *(const bf16x8*)&hc0[off];
                aLo[ks] = *(const bf16x8*)&hc1[off];
            }

            f32x4 acc[3];
#pragma unroll
            for (int g = 0; g < 3; ++g) acc[g] = (f32x4){0.f, 0.f, 0.f, 0.f};
#pragma unroll
            for (int g = 0; g < 3; ++g)
#pragma unroll
                for (int ks = 0; ks < 4; ++ks) {
                    acc[g] = __builtin_amdgcn_mfma_f32_16x16x32_bf16(aHi[ks], bh[g][ks], acc[g], 0, 0, 0);
                    acc[g] = __builtin_amdgcn_mfma_f32_16x16x32_bf16(aHi[ks], bl[g][ks], acc[g], 0, 0, 0);
                    acc[g] = __builtin_amdgcn_mfma_f32_16x16x32_bf16(aLo[ks], bh[g][ks], acc[g], 0, 0, 0);
                }

            // ---- epilogue for this group's 4 cells ----
#pragma unroll
            for (int r = 0; r < 4; ++r) {
                int c = G * 4 + r;
                int off2 = (16 * G + 4 * q + r) * 136 + jc;
                float hold = bf2f(hc0[off2]) + bf2f(hc1[off2]);
                float pr = wx[c][0] + acc[0][r] + bhr;
                float pz = wx[c][1] + acc[1][r] + bhz;
                float rr = __builtin_amdgcn_rcpf(1.f + __expf(-pr));
                float zz = __builtin_amdgcn_rcpf(1.f + __expf(-pz));
                float pn = wx[c][2] + rr * (acc[2][r] + bhn);
                float th = 1.f - 2.f * __builtin_amdgcn_rcpf(1.f + __expf(2.f * pn));
                float hnew = (1.f - zz) * th + zz * hold;
                if (jok) {
                    short hi = f2bf(hnew);
                    hn0[off2] = hi;
                    hn1[off2] = f2bf(hnew - bf2f(hi));
                }
            }
        }
        __syncthreads();
        cur ^= 1;
    }

    for (int i = tid; i < 64 * 100; i += 448) {
        int nd = i / 100, c = i % 100;
        if (node0 + nd < n_nodes)
            hout[(long)(node0 + nd) * 100 + c] =
                bf2f(hA[cur][0][nd * 136 + c]) + bf2f(hA[cur][1][nd * 136 + c]);
    }
}

// ---------------------------------------------------------------------------
// Degree (int atomics)
// ---------------------------------------------------------------------------
__global__ void k_deg(const int* __restrict__ dst, int* __restrict__ degi, int E) {
    int e = blockIdx.x * blockDim.x + threadIdx.x;
    if (e < E) atomicAdd(&degi[dst[e]], 1);
}

// ---------------------------------------------------------------------------
// Single-block scan: row_start/cursor = exclusive prefix of degi; dinv fused.
// ---------------------------------------------------------------------------
__global__ __launch_bounds__(1024) void k_scan(const int* __restrict__ degi,
                                               int* __restrict__ rs, int* __restrict__ cursor,
                                               float* __restrict__ dinv, int N, int E) {
    __shared__ int part[1024];
    int tid = threadIdx.x;
    int chunk = (N + 1023) / 1024;
    int lo = tid * chunk, hi = lo + chunk;
    if (lo > N) lo = N;
    if (hi > N) hi = N;
    int s = 0;
    for (int i = lo; i < hi; ++i) s += degi[i];
    part[tid] = s;
    __syncthreads();
    for (int off = 1; off < 1024; off <<= 1) {
        int add = (tid >= off) ? part[tid - off] : 0;
        __syncthreads();
        part[tid] += add;
        __syncthreads();
    }
    int run = (tid > 0) ? part[tid - 1] : 0;
    for (int i = lo; i < hi; ++i) {
        rs[i] = run;
        cursor[i] = run;
        int d = degi[i];
        dinv[i] = rsqrtf((float)d + 1.0f);
        run += d;
    }
    if (tid == 0) rs[N] = E;
}

// ---------------------------------------------------------------------------
// Scatter edges into CSR order (by dst)
// ---------------------------------------------------------------------------
__global__ void k_scatter(const int* __restrict__ src, const int* __restrict__ dst,
                          int* __restrict__ cursor, int* __restrict__ esrc, int E) {
    int e = blockIdx.x * blockDim.x + threadIdx.x;
    if (e >= E) return;
    int pos = atomicAdd(&cursor[dst[e]], 1);
    esrc[pos] = src[e];
}

// ---------------------------------------------------------------------------
// xw[n, 4jq..] = x[n,:] @ W[:, 4jq..] — float4 output quads, b128 LDS reads.
// ---------------------------------------------------------------------------
template <int K>
__global__ __launch_bounds__(256) void k_mm(const float* __restrict__ x,
                                            const float* __restrict__ W,
                                            float* __restrict__ out, int nquads) {
    __shared__ float sW[K * 100];
    for (int i = threadIdx.x; i < K * 100; i += 256) sW[i] = W[i];
    __syncthreads();
    int end = blockIdx.x * 2048 + 2048;
    if (end > nquads) end = nquads;
    for (int t = blockIdx.x * 2048 + threadIdx.x; t < end; t += 256) {
        int n = t / 25, jq = t % 25;
        const float4* xr = (const float4*)(x + (long)n * K);
        float4 acc = {0.f, 0.f, 0.f, 0.f};
#pragma unroll 4
        for (int d4 = 0; d4 < K / 4; ++d4) {
            float4 xv = xr[d4];
            float4 w0 = *(const float4*)&sW[(4 * d4 + 0) * 100 + 4 * jq];
            float4 w1 = *(const float4*)&sW[(4 * d4 + 1) * 100 + 4 * jq];
            float4 w2 = *(const float4*)&sW[(4 * d4 + 2) * 100 + 4 * jq];
            float4 w3 = *(const float4*)&sW[(4 * d4 + 3) * 100 + 4 * jq];
            acc.x = fmaf(xv.x, w0.x, fmaf(xv.y, w1.x, fmaf(xv.z, w2.x, fmaf(xv.w, w3.x, acc.x))));
            acc.y = fmaf(xv.x, w0.y, fmaf(xv.y, w1.y, fmaf(xv.z, w2.y, fmaf(xv.w, w3.y, acc.y))));
            acc.z = fmaf(xv.x, w0.z, fmaf(xv.y, w1.z, fmaf(xv.z, w2.z, fmaf(xv.w, w3.z, acc.z))));
            acc.w = fmaf(xv.x, w0.w, fmaf(xv.y, w1.w, fmaf(xv.z, w2.w, fmaf(xv.w, w3.w, acc.w))));
        }
        ((float4*)out)[t] = acc;
    }
}

// ---------------------------------------------------------------------------
// Conv1 finish: CSR gather (no atomics) + self term + bias, then
// xc1 = v ; xbig = relu([v, hn[idx]]).  Thread per (n, jq).
// ---------------------------------------------------------------------------
__global__ void k_conv1_fin(const int* __restrict__ rs, const int* __restrict__ esrc,
                            const float* __restrict__ xw, const float* __restrict__ dinv,
                            const float* __restrict__ b1, const float* __restrict__ hn,
                            const int* __restrict__ idx, float* __restrict__ xc1,
                            float* __restrict__ xbig, int N) {
    int t = blockIdx.x * blockDim.x + threadIdx.x;
    if (t >= N * 25) return;
    int n = t / 25, jq = t % 25;
    float dn = dinv[n];
    float4 acc = {0.f, 0.f, 0.f, 0.f};
    int e1 = rs[n + 1];
    for (int e = rs[n]; e < e1; ++e) {
        int s = esrc[e];
        float ds = dinv[s];
        float4 xs = ((const float4*)xw)[s * 25 + jq];
        acc.x = fmaf(xs.x, ds, acc.x);
        acc.y = fmaf(xs.y, ds, acc.y);
        acc.z = fmaf(xs.z, ds, acc.z);
        acc.w = fmaf(xs.w, ds, acc.w);
    }
    float4 xs = ((const float4*)xw)[t];
    float4 bq = ((const float4*)b1)[jq];
    float dn2 = dn * dn;
    float4 v;
    v.x = fmaf(acc.x, dn, fmaf(xs.x, dn2, bq.x));
    v.y = fmaf(acc.y, dn, fmaf(xs.y, dn2, bq.y));
    v.z = fmaf(acc.z, dn, fmaf(xs.z, dn2, bq.z));
    v.w = fmaf(acc.w, dn, fmaf(xs.w, dn2, bq.w));
    ((float4*)xc1)[t] = v;
    float4 rv = ((const float4*)hn)[(long)idx[n] * 25 + jq];
    float4 a = {fmaxf(v.x, 0.f), fmaxf(v.y, 0.f), fmaxf(v.z, 0.f), fmaxf(v.w, 0.f)};
    float4 b = {fmaxf(rv.x, 0.f), fmaxf(rv.y, 0.f), fmaxf(rv.z, 0.f), fmaxf(rv.w, 0.f)};
    ((float4*)xbig)[n * 50 + jq] = a;
    ((float4*)xbig)[n * 50 + 25 + jq] = b;
}

// ---------------------------------------------------------------------------
// Conv2 finish: out = [relu(agg2 + self + b2), xc1[idx]]
// ---------------------------------------------------------------------------
__global__ void k_conv2_fin(const int* __restrict__ rs, const int* __restrict__ esrc,
                            const float* __restrict__ xw, const float* __restrict__ dinv,
                            const float* __restrict__ b2, const float* __restrict__ xc1,
                            const int* __restrict__ idx, float* __restrict__ out, int N) {
    int t = blockIdx.x * blockDim.x + threadIdx.x;
    if (t >= N * 25) return;
    int n = t / 25, jq = t % 25;
    float dn = dinv[n];
    float4 acc = {0.f, 0.f, 0.f, 0.f};
    int e1 = rs[n + 1];
    for (int e = rs[n]; e < e1; ++e) {
        int s = esrc[e];
        float ds = dinv[s];
        float4 xs = ((const float4*)xw)[s * 25 + jq];
        acc.x = fmaf(xs.x, ds, acc.x);
        acc.y = fmaf(xs.y, ds, acc.y);
        acc.z = fmaf(xs.z, ds, acc.z);
        acc.w = fmaf(xs.w, ds, acc.w);
    }
    float4 xs = ((const float4*)xw)[t];
    float4 bq = ((const float4*)b2)[jq];
    float dn2 = dn * dn;
    float4 v;
    v.x = fmaxf(fmaf(acc.x, dn, fmaf(xs.x, dn2, bq.x)), 0.f);
    v.y = fmaxf(fmaf(acc.y, dn, fmaf(xs.y, dn2, bq.y)), 0.f);
    v.z = fmaxf(fmaf(acc.z, dn, fmaf(xs.z, dn2, bq.z)), 0.f);
    v.w = fmaxf(fmaf(acc.w, dn, fmaf(xs.w, dn2, bq.w)), 0.f);
    float4 rv = ((const float4*)xc1)[(long)idx[n] * 25 + jq];
    ((float4*)out)[n * 50 + jq] = v;
    ((float4*)out)[n * 50 + 25 + jq] = rv;
}

// ---------------------------------------------------------------------------
extern "C" void kernel_launch(void* const* d_in, const int* in_sizes, int n_in,
                              void* d_out, int out_size, void* d_ws, size_t ws_size,
                              hipStream_t stream) {
    const int*   feat    = (const int*)d_in[0];
    const int*   edges   = (const int*)d_in[1];
    const int*   indices = (const int*)d_in[2];
    const float* h0      = (const float*)d_in[3];
    const float* emb     = (const float*)d_in[4];
    const float* W_ih    = (const float*)d_in[5];
    const float* W_hh    = (const float*)d_in[6];
    const float* b_ih    = (const float*)d_in[7];
    const float* b_hh    = (const float*)d_in[8];
    const float* W1      = (const float*)d_in[9];
    const float* b1      = (const float*)d_in[10];
    const float* W2      = (const float*)d_in[11];
    const float* b2      = (const float*)d_in[12];
    float* out = (float*)d_out;

    const int N = in_sizes[2];
    const int E = in_sizes[1] / 2;
    const int V = in_sizes[4] / D_IN;
    const int* src = edges;
    const int* dst = edges + E;

    float* ws   = (float*)d_ws;
    float* hbuf = ws;                         // N*100
    float* Wemb = hbuf + (long)N * H;         // V*300 (reused as xw after GRU)
    float* xw   = Wemb;                       // reuse: N*100
    float* xc1  = Wemb + (long)V * 300;       // N*100
    float* xbig = xc1 + (long)N * 100;        // N*200
    float* dinv = xbig + (long)N * 200;       // N
    short* Bhi  = (short*)(dinv + N);         // 43008 bf16
    short* Blo  = Bhi + 43008;                // 43008 bf16
    int*   degi = (int*)(Blo + 43008);        // N
    int*   rs   = degi + N;                   // N+1
    int*   cursor = rs + N + 1;               // N
    int*   esrc = cursor + N;                 // E
    (void)ws_size; (void)n_in; (void)out_size;

    const int B = 256;

    hipMemsetAsync(degi, 0, (size_t)N * sizeof(int), stream);
    k_deg<<<(E + B - 1) / B, B, 0, stream>>>(dst, degi, E);
    k_scan<<<1, 1024, 0, stream>>>(degi, rs, cursor, dinv, N, E);
    k_scatter<<<(E + B - 1) / B, B, 0, stream>>>(src, dst, cursor, esrc, E);

    k_bpack<<<(43008 + B - 1) / B, B, 0, stream>>>(W_hh, Bhi, Blo, 43008);
    k_wemb_t<<<(V + 63) / 64, 512, 0, stream>>>(emb, W_ih, b_ih, Wemb, V);

    k_gru_mfma<<<(N + 63) / 64, 448, 0, stream>>>(feat, h0, Wemb, Bhi, Blo, b_hh, hbuf, N);

    {
        int nquads = N * 25;
        k_mm<100><<<(nquads + 2047) / 2048, 256, 0, stream>>>(hbuf, W1, xw, nquads);
        k_conv1_fin<<<(nquads + B - 1) / B, B, 0, stream>>>(rs, esrc, xw, dinv, b1, hbuf,
                                                            indices, xc1, xbig, N);
        k_mm<200><<<(nquads + 2047) / 2048, 256, 0, stream>>>(xbig, W2, xw, nquads);
        k_conv2_fin<<<(nquads + B - 1) / B, B, 0, stream>>>(rs, esrc, xw, dinv, b2, xc1,
                                                            indices, out, N);
    }
}

// Round 7
// 1698.291 us; speedup vs baseline: 1.4708x; 1.4708x over previous
//
#include <hip/hip_runtime.h>
#include <math.h>

#define D_IN 100
#define H    100
#define SEQL 30

typedef __attribute__((ext_vector_type(8))) short bf16x8;
typedef __attribute__((ext_vector_type(4))) float f32x4;

__device__ __forceinline__ short f2bf(float f) {
    unsigned u = __builtin_bit_cast(unsigned, f);
    unsigned r = (u + 0x7FFFu + ((u >> 16) & 1u)) >> 16;
    return (short)r;
}
__device__ __forceinline__ float bf2f(short s) {
    unsigned u = ((unsigned)(unsigned short)s) << 16;
    return __builtin_bit_cast(float, u);
}

// ---------------------------------------------------------------------------
// Wemb = emb @ W_ih^T + b_ih  (round-5 one-row version; the round-6 two-row
// variant spilled ~4 GB of scratch traffic -> reverted).
// ---------------------------------------------------------------------------
__global__ __launch_bounds__(512) void k_wemb_t(const float* __restrict__ emb,
                                                const float* __restrict__ W_ih,
                                                const float* __restrict__ b_ih,
                                                float* __restrict__ Wemb, int V) {
    __shared__ float sWT[100 * 300];   // [d][g], 120KB
    __shared__ float sb[300];
    for (int i = threadIdx.x; i < 30000; i += 512) {
        int g = i / 100, d = i % 100;
        sWT[d * 300 + g] = W_ih[i];
    }
    for (int i = threadIdx.x; i < 300; i += 512) sb[i] = b_ih[i];
    __syncthreads();

    int v0 = blockIdx.x * 64;
    for (int t = threadIdx.x; t < 64 * 75; t += 512) {
        int vl = t / 75, gq = t % 75;
        int v = v0 + vl;
        if (v >= V) continue;
        const float4* e = (const float4*)(emb + (long)v * 100);
        float4 acc = *(const float4*)&sb[4 * gq];
#pragma unroll
        for (int d4 = 0; d4 < 25; ++d4) {
            float4 ev = e[d4];
            float4 w0 = *(const float4*)&sWT[(4 * d4 + 0) * 300 + 4 * gq];
            float4 w1 = *(const float4*)&sWT[(4 * d4 + 1) * 300 + 4 * gq];
            float4 w2 = *(const float4*)&sWT[(4 * d4 + 2) * 300 + 4 * gq];
            float4 w3 = *(const float4*)&sWT[(4 * d4 + 3) * 300 + 4 * gq];
            acc.x = fmaf(ev.x, w0.x, fmaf(ev.y, w1.x, fmaf(ev.z, w2.x, fmaf(ev.w, w3.x, acc.x))));
            acc.y = fmaf(ev.x, w0.y, fmaf(ev.y, w1.y, fmaf(ev.z, w2.y, fmaf(ev.w, w3.y, acc.y))));
            acc.z = fmaf(ev.x, w0.z, fmaf(ev.y, w1.z, fmaf(ev.z, w2.z, fmaf(ev.w, w3.z, acc.z))));
            acc.w = fmaf(ev.x, w0.w, fmaf(ev.y, w1.w, fmaf(ev.z, w2.w, fmaf(ev.w, w3.w, acc.w))));
        }
        *(float4*)(Wemb + (long)v * 300 + 4 * gq) = acc;
    }
}

// ---------------------------------------------------------------------------
// Pack W_hh^T into MFMA-B-fragment-major bf16 hi/lo tables (layout verified).
// ---------------------------------------------------------------------------
__global__ void k_bpack(const float* __restrict__ W_hh, short* __restrict__ Bhi,
                        short* __restrict__ Blo, int total /* 43008 */) {
    int t = blockIdx.x * blockDim.x + threadIdx.x;
    if (t >= total) return;
    int i    = t & 7;
    int lane = (t >> 3) & 63;
    int blk  = t >> 9;            // nt*4 + ks
    int ks = blk & 3, nt = blk >> 2;
    int np = nt * 16 + (lane & 15);
    int k  = ks * 32 + ((lane >> 4) << 3) + i;
    int g = np / 112, j = np % 112;
    float v = (j < 100 && k < 100) ? W_hh[(g * 100 + j) * 100 + k] : 0.f;
    short hi = f2bf(v);
    short lo = f2bf(v - bf2f(hi));
    Bhi[t] = hi;
    Blo[t] = lo;
}

// ---------------------------------------------------------------------------
// MFMA GRU round 7: 16 nodes/block, 7 waves (r5 structure, B frags register-
// resident, verified). NEW: per-step Wemb rows staged COALESCED into a
// double-buffered LDS tile (swx), one step ahead:
//  - r5/r6 gathered 12 scattered dwords/lane/step -> ~1350 cache-line
//    micro-requests per CU-step on the L1 path (4.4x the 304-line minimum);
//    that throughput term scaled with work and was the wall (r6 neutral).
//  - Staged: 19 coalesced dwordx4 wave-instrs/block-step, each line fetched
//    once, and a FULL step of slack before consumption -> latency gone.
// Tokens pipelined 2 steps deep via LDS stok. 1 barrier/step. hprev in regs.
// swx row stride 308 dw (16B-aligned; epilogue banks: q -> 16q mod 32 =
// 2-way, free; staging b128 writes 2-way).
// ---------------------------------------------------------------------------
__global__ __launch_bounds__(448, 2) void k_gru_mfma(
        const int* __restrict__ tok, const float* __restrict__ h0,
        const float* __restrict__ Wemb, const short* __restrict__ Bhi,
        const short* __restrict__ Blo, const float* __restrict__ b_hh,
        float* __restrict__ hout, int n_nodes) {
    __shared__ short hA[2][2][16 * 136];   // 17.4 KB
    __shared__ float swx[2][16 * 308];     // 39.4 KB
    __shared__ int   stok[2][16];          // pre-scaled token*300

    const int tid  = threadIdx.x;
    const int w    = tid >> 6;
    const int lane = tid & 63;
    const int n0   = lane & 15;
    const int q    = lane >> 4;
    const int node0 = blockIdx.x * 16;

    // ---- B fragments: 3 gates x 4 k-steps, hi+lo, loaded once ----
    bf16x8 bh[3][4], bl[3][4];
#pragma unroll
    for (int g = 0; g < 3; ++g)
#pragma unroll
        for (int ks = 0; ks < 4; ++ks) {
            long bo = ((long)((g * 7 + w) * 4 + ks) * 64 + lane) * 8;
            bh[g][ks] = *(const bf16x8*)&Bhi[bo];
            bl[g][ks] = *(const bf16x8*)&Blo[bo];
        }

    // ---- init h tables (buffer 1 zeroed so its k-pad stays 0) ----
    for (int i = tid; i < 16 * 128; i += 448) {
        int nd = i >> 7, c = i & 127;
        int row = node0 + nd; if (row >= n_nodes) row = n_nodes - 1;
        float v = (c < 100) ? h0[(long)row * 100 + c] : 0.f;
        short hi = f2bf(v);
        hA[0][0][nd * 136 + c] = hi;
        hA[0][1][nd * 136 + c] = f2bf(v - bf2f(hi));
        hA[1][0][nd * 136 + c] = 0;
        hA[1][1][nd * 136 + c] = 0;
    }

    const int j   = 16 * w + n0;
    const int jc  = j < 100 ? j : 99;
    const bool jok = (j < 100);
    const float bhr = b_hh[jc], bhz = b_hh[100 + jc], bhn = b_hh[200 + jc];

    int rows[4];
#pragma unroll
    for (int r = 0; r < 4; ++r) {
        int row = node0 + 4 * q + r;
        rows[r] = row < n_nodes ? row : n_nodes - 1;
    }
    float hprev[4];
#pragma unroll
    for (int r = 0; r < 4; ++r) hprev[r] = h0[(long)rows[r] * 100 + jc];

    // ---- pre-stage: swx[0] <- wx(step 0); stok[1] <- tokens(step 1) ----
    if (tid < 16) {
        int row = node0 + tid; if (row >= n_nodes) row = n_nodes - 1;
        stok[1][tid] = tok[(long)row * SEQL + 1] * 300;
    }
    for (int i = tid; i < 16 * 75; i += 448) {
        int nd = i / 75, qd = i % 75;
        int row = node0 + nd; if (row >= n_nodes) row = n_nodes - 1;
        long tb = (long)tok[(long)row * SEQL] * 300;
        *(float4*)&swx[0][nd * 308 + 4 * qd] = *(const float4*)(Wemb + tb + 4 * qd);
    }
    __syncthreads();

    int cur = 0;
#pragma unroll 1
    for (int l = 0; l < SEQL; ++l) {
        const short* hc0 = &hA[cur][0][0];
        const short* hc1 = &hA[cur][1][0];
        short* hn0 = &hA[cur ^ 1][0][0];
        short* hn1 = &hA[cur ^ 1][1][0];
        const float* wxs = &swx[cur][0];

        // ---- A-fragments ----
        bf16x8 aHi[4], aLo[4];
#pragma unroll
        for (int ks = 0; ks < 4; ++ks) {
            int off = n0 * 136 + ks * 32 + q * 8;
            aHi[ks] = *(const bf16x8*)&hc0[off];
            aLo[ks] = *(const bf16x8*)&hc1[off];
        }
        // ---- wx for this step from LDS (2-way banks, ds_read2 pairs) ----
        float wxr[4], wxz[4], wxn_[4];
#pragma unroll
        for (int r = 0; r < 4; ++r) {
            const float* wp = wxs + (4 * q + r) * 308 + jc;
            wxr[r]  = wp[0];
            wxz[r]  = wp[100];
            wxn_[r] = wp[200];
        }

        // ---- stage next step's wx (full-step slack; coalesced) ----
        if (l < SEQL - 1) {
            float* dst = &swx[cur ^ 1][0];
#pragma unroll 1
            for (int i = tid; i < 16 * 75; i += 448) {
                int nd = i / 75, qd = i % 75;
                long tb = (long)stok[cur ^ 1][nd];
                *(float4*)&dst[nd * 308 + 4 * qd] = *(const float4*)(Wemb + tb + 4 * qd);
            }
        }
        // ---- tokens for step l+2 ----
        if (l < SEQL - 2 && tid < 16) {
            int row = node0 + tid; if (row >= n_nodes) row = n_nodes - 1;
            stok[cur][tid] = tok[(long)row * SEQL + l + 2] * 300;
        }

        // ---- MFMA: 3 gates x 4 k-steps x 3 split products ----
        f32x4 acc[3];
#pragma unroll
        for (int g = 0; g < 3; ++g) acc[g] = (f32x4){0.f, 0.f, 0.f, 0.f};
#pragma unroll
        for (int g = 0; g < 3; ++g)
#pragma unroll
            for (int ks = 0; ks < 4; ++ks) {
                acc[g] = __builtin_amdgcn_mfma_f32_16x16x32_bf16(aHi[ks], bh[g][ks], acc[g], 0, 0, 0);
                acc[g] = __builtin_amdgcn_mfma_f32_16x16x32_bf16(aHi[ks], bl[g][ks], acc[g], 0, 0, 0);
                acc[g] = __builtin_amdgcn_mfma_f32_16x16x32_bf16(aLo[ks], bh[g][ks], acc[g], 0, 0, 0);
            }

        // ---- epilogue (wave-local; hprev register-carried) ----
#pragma unroll
        for (int r = 0; r < 4; ++r) {
            float pr = wxr[r]  + acc[0][r] + bhr;
            float pz = wxz[r]  + acc[1][r] + bhz;
            float rr = __builtin_amdgcn_rcpf(1.f + __expf(-pr));
            float zz = __builtin_amdgcn_rcpf(1.f + __expf(-pz));
            float pn = wxn_[r] + rr * (acc[2][r] + bhn);
            float th = 1.f - 2.f * __builtin_amdgcn_rcpf(1.f + __expf(2.f * pn));
            float hnew = (1.f - zz) * th + zz * hprev[r];
            hprev[r] = hnew;
            if (jok) {
                int off = (4 * q + r) * 136 + j;
                short hi = f2bf(hnew);
                hn0[off] = hi;
                hn1[off] = f2bf(hnew - bf2f(hi));
            }
        }
        __syncthreads();
        cur ^= 1;
    }

    for (int i = tid; i < 16 * 100; i += 448) {
        int nd = i / 100, c = i % 100;
        if (node0 + nd < n_nodes)
            hout[(long)(node0 + nd) * 100 + c] =
                bf2f(hA[cur][0][nd * 136 + c]) + bf2f(hA[cur][1][nd * 136 + c]);
    }
}

// ---------------------------------------------------------------------------
// Degree (int atomics)
// ---------------------------------------------------------------------------
__global__ void k_deg(const int* __restrict__ dst, int* __restrict__ degi, int E) {
    int e = blockIdx.x * blockDim.x + threadIdx.x;
    if (e < E) atomicAdd(&degi[dst[e]], 1);
}

// ---------------------------------------------------------------------------
// Single-block scan: row_start/cursor = exclusive prefix of degi; dinv fused.
// ---------------------------------------------------------------------------
__global__ __launch_bounds__(1024) void k_scan(const int* __restrict__ degi,
                                               int* __restrict__ rs, int* __restrict__ cursor,
                                               float* __restrict__ dinv, int N, int E) {
    __shared__ int part[1024];
    int tid = threadIdx.x;
    int chunk = (N + 1023) / 1024;
    int lo = tid * chunk, hi = lo + chunk;
    if (lo > N) lo = N;
    if (hi > N) hi = N;
    int s = 0;
    for (int i = lo; i < hi; ++i) s += degi[i];
    part[tid] = s;
    __syncthreads();
    for (int off = 1; off < 1024; off <<= 1) {
        int add = (tid >= off) ? part[tid - off] : 0;
        __syncthreads();
        part[tid] += add;
        __syncthreads();
    }
    int run = (tid > 0) ? part[tid - 1] : 0;
    for (int i = lo; i < hi; ++i) {
        rs[i] = run;
        cursor[i] = run;
        int d = degi[i];
        dinv[i] = rsqrtf((float)d + 1.0f);
        run += d;
    }
    if (tid == 0) rs[N] = E;
}

// ---------------------------------------------------------------------------
// Scatter edges into CSR order (by dst)
// ---------------------------------------------------------------------------
__global__ void k_scatter(const int* __restrict__ src, const int* __restrict__ dst,
                          int* __restrict__ cursor, int* __restrict__ esrc, int E) {
    int e = blockIdx.x * blockDim.x + threadIdx.x;
    if (e >= E) return;
    int pos = atomicAdd(&cursor[dst[e]], 1);
    esrc[pos] = src[e];
}

// ---------------------------------------------------------------------------
// xw[n, 4jq..] = x[n,:] @ W[:, 4jq..] — float4 output quads, b128 LDS reads.
// ---------------------------------------------------------------------------
template <int K>
__global__ __launch_bounds__(256) void k_mm(const float* __restrict__ x,
                                            const float* __restrict__ W,
                                            float* __restrict__ out, int nquads) {
    __shared__ float sW[K * 100];
    for (int i = threadIdx.x; i < K * 100; i += 256) sW[i] = W[i];
    __syncthreads();
    int end = blockIdx.x * 2048 + 2048;
    if (end > nquads) end = nquads;
    for (int t = blockIdx.x * 2048 + threadIdx.x; t < end; t += 256) {
        int n = t / 25, jq = t % 25;
        const float4* xr = (const float4*)(x + (long)n * K);
        float4 acc = {0.f, 0.f, 0.f, 0.f};
#pragma unroll 4
        for (int d4 = 0; d4 < K / 4; ++d4) {
            float4 xv = xr[d4];
            float4 w0 = *(const float4*)&sW[(4 * d4 + 0) * 100 + 4 * jq];
            float4 w1 = *(const float4*)&sW[(4 * d4 + 1) * 100 + 4 * jq];
            float4 w2 = *(const float4*)&sW[(4 * d4 + 2) * 100 + 4 * jq];
            float4 w3 = *(const float4*)&sW[(4 * d4 + 3) * 100 + 4 * jq];
            acc.x = fmaf(xv.x, w0.x, fmaf(xv.y, w1.x, fmaf(xv.z, w2.x, fmaf(xv.w, w3.x, acc.x))));
            acc.y = fmaf(xv.x, w0.y, fmaf(xv.y, w1.y, fmaf(xv.z, w2.y, fmaf(xv.w, w3.y, acc.y))));
            acc.z = fmaf(xv.x, w0.z, fmaf(xv.y, w1.z, fmaf(xv.z, w2.z, fmaf(xv.w, w3.z, acc.z))));
            acc.w = fmaf(xv.x, w0.w, fmaf(xv.y, w1.w, fmaf(xv.z, w2.w, fmaf(xv.w, w3.w, acc.w))));
        }
        ((float4*)out)[t] = acc;
    }
}

// ---------------------------------------------------------------------------
// Conv1 finish: CSR gather (no atomics) + self term + bias, then
// xc1 = v ; xbig = relu([v, hn[idx]]).
// ---------------------------------------------------------------------------
__global__ void k_conv1_fin(const int* __restrict__ rs, const int* __restrict__ esrc,
                            const float* __restrict__ xw, const float* __restrict__ dinv,
                            const float* __restrict__ b1, const float* __restrict__ hn,
                            const int* __restrict__ idx, float* __restrict__ xc1,
                            float* __restrict__ xbig, int N) {
    int t = blockIdx.x * blockDim.x + threadIdx.x;
    if (t >= N * 25) return;
    int n = t / 25, jq = t % 25;
    float dn = dinv[n];
    float4 acc = {0.f, 0.f, 0.f, 0.f};
    int e1 = rs[n + 1];
    for (int e = rs[n]; e < e1; ++e) {
        int s = esrc[e];
        float ds = dinv[s];
        float4 xs = ((const float4*)xw)[s * 25 + jq];
        acc.x = fmaf(xs.x, ds, acc.x);
        acc.y = fmaf(xs.y, ds, acc.y);
        acc.z = fmaf(xs.z, ds, acc.z);
        acc.w = fmaf(xs.w, ds, acc.w);
    }
    float4 xs = ((const float4*)xw)[t];
    float4 bq = ((const float4*)b1)[jq];
    float dn2 = dn * dn;
    float4 v;
    v.x = fmaf(acc.x, dn, fmaf(xs.x, dn2, bq.x));
    v.y = fmaf(acc.y, dn, fmaf(xs.y, dn2, bq.y));
    v.z = fmaf(acc.z, dn, fmaf(xs.z, dn2, bq.z));
    v.w = fmaf(acc.w, dn, fmaf(xs.w, dn2, bq.w));
    ((float4*)xc1)[t] = v;
    float4 rv = ((const float4*)hn)[(long)idx[n] * 25 + jq];
    float4 a = {fmaxf(v.x, 0.f), fmaxf(v.y, 0.f), fmaxf(v.z, 0.f), fmaxf(v.w, 0.f)};
    float4 b = {fmaxf(rv.x, 0.f), fmaxf(rv.y, 0.f), fmaxf(rv.z, 0.f), fmaxf(rv.w, 0.f)};
    ((float4*)xbig)[n * 50 + jq] = a;
    ((float4*)xbig)[n * 50 + 25 + jq] = b;
}

// ---------------------------------------------------------------------------
// Conv2 finish: out = [relu(agg2 + self + b2), xc1[idx]]
// ---------------------------------------------------------------------------
__global__ void k_conv2_fin(const int* __restrict__ rs, const int* __restrict__ esrc,
                            const float* __restrict__ xw, const float* __restrict__ dinv,
                            const float* __restrict__ b2, const float* __restrict__ xc1,
                            const int* __restrict__ idx, float* __restrict__ out, int N) {
    int t = blockIdx.x * blockDim.x + threadIdx.x;
    if (t >= N * 25) return;
    int n = t / 25, jq = t % 25;
    float dn = dinv[n];
    float4 acc = {0.f, 0.f, 0.f, 0.f};
    int e1 = rs[n + 1];
    for (int e = rs[n]; e < e1; ++e) {
        int s = esrc[e];
        float ds = dinv[s];
        float4 xs = ((const float4*)xw)[s * 25 + jq];
        acc.x = fmaf(xs.x, ds, acc.x);
        acc.y = fmaf(xs.y, ds, acc.y);
        acc.z = fmaf(xs.z, ds, acc.z);
        acc.w = fmaf(xs.w, ds, acc.w);
    }
    float4 xs = ((const float4*)xw)[t];
    float4 bq = ((const float4*)b2)[jq];
    float dn2 = dn * dn;
    float4 v;
    v.x = fmaxf(fmaf(acc.x, dn, fmaf(xs.x, dn2, bq.x)), 0.f);
    v.y = fmaxf(fmaf(acc.y, dn, fmaf(xs.y, dn2, bq.y)), 0.f);
    v.z = fmaxf(fmaf(acc.z, dn, fmaf(xs.z, dn2, bq.z)), 0.f);
    v.w = fmaxf(fmaf(acc.w, dn, fmaf(xs.w, dn2, bq.w)), 0.f);
    float4 rv = ((const float4*)xc1)[(long)idx[n] * 25 + jq];
    ((float4*)out)[n * 50 + jq] = v;
    ((float4*)out)[n * 50 + 25 + jq] = rv;
}

// ---------------------------------------------------------------------------
extern "C" void kernel_launch(void* const* d_in, const int* in_sizes, int n_in,
                              void* d_out, int out_size, void* d_ws, size_t ws_size,
                              hipStream_t stream) {
    const int*   feat    = (const int*)d_in[0];
    const int*   edges   = (const int*)d_in[1];
    const int*   indices = (const int*)d_in[2];
    const float* h0      = (const float*)d_in[3];
    const float* emb     = (const float*)d_in[4];
    const float* W_ih    = (const float*)d_in[5];
    const float* W_hh    = (const float*)d_in[6];
    const float* b_ih    = (const float*)d_in[7];
    const float* b_hh    = (const float*)d_in[8];
    const float* W1      = (const float*)d_in[9];
    const float* b1      = (const float*)d_in[10];
    const float* W2      = (const float*)d_in[11];
    const float* b2      = (const float*)d_in[12];
    float* out = (float*)d_out;

    const int N = in_sizes[2];
    const int E = in_sizes[1] / 2;
    const int V = in_sizes[4] / D_IN;
    const int* src = edges;
    const int* dst = edges + E;

    float* ws   = (float*)d_ws;
    float* hbuf = ws;                         // N*100
    float* Wemb = hbuf + (long)N * H;         // V*300 (reused as xw after GRU)
    float* xw   = Wemb;                       // reuse: N*100
    float* xc1  = Wemb + (long)V * 300;       // N*100
    float* xbig = xc1 + (long)N * 100;        // N*200
    float* dinv = xbig + (long)N * 200;       // N
    short* Bhi  = (short*)(dinv + N);         // 43008 bf16
    short* Blo  = Bhi + 43008;                // 43008 bf16
    int*   degi = (int*)(Blo + 43008);        // N
    int*   rs   = degi + N;                   // N+1
    int*   cursor = rs + N + 1;               // N
    int*   esrc = cursor + N;                 // E
    (void)ws_size; (void)n_in; (void)out_size;

    const int B = 256;

    hipMemsetAsync(degi, 0, (size_t)N * sizeof(int), stream);
    k_deg<<<(E + B - 1) / B, B, 0, stream>>>(dst, degi, E);
    k_scan<<<1, 1024, 0, stream>>>(degi, rs, cursor, dinv, N, E);
    k_scatter<<<(E + B - 1) / B, B, 0, stream>>>(src, dst, cursor, esrc, E);

    k_bpack<<<(43008 + B - 1) / B, B, 0, stream>>>(W_hh, Bhi, Blo, 43008);
    k_wemb_t<<<(V + 63) / 64, 512, 0, stream>>>(emb, W_ih, b_ih, Wemb, V);

    k_gru_mfma<<<(N + 15) / 16, 448, 0, stream>>>(feat, h0, Wemb, Bhi, Blo, b_hh, hbuf, N);

    {
        int nquads = N * 25;
        k_mm<100><<<(nquads + 2047) / 2048, 256, 0, stream>>>(hbuf, W1, xw, nquads);
        k_conv1_fin<<<(nquads + B - 1) / B, B, 0, stream>>>(rs, esrc, xw, dinv, b1, hbuf,
                                                            indices, xc1, xbig, N);
        k_mm<200><<<(nquads + 2047) / 2048, 256, 0, stream>>>(xbig, W2, xw, nquads);
        k_conv2_fin<<<(nquads + B - 1) / B, B, 0, stream>>>(rs, esrc, xw, dinv, b2, xc1,
                                                            indices, out, N);
    }
}